// Round 15
// baseline (1580.805 us; speedup 1.0000x reference)
//
#include <hip/hip_runtime.h>
#include <math.h>

#define NN 50000
#define EE 800000
#define OO 4
#define CC 64
#define KDD 16
#define KEYDD 128
#define CH 16  // gather window per chunk (pipelined across chunks)

typedef float v2f __attribute__((ext_vector_type(2)));

// Full-wave (64-lane) sum via DPP builtins (prologue only)
__device__ __forceinline__ float wave_red_sum(float v) {
  int x;
  x = __builtin_amdgcn_update_dpp(0, __float_as_int(v), 0x111, 0xf, 0xf, false);
  v += __int_as_float(x);
  x = __builtin_amdgcn_update_dpp(0, __float_as_int(v), 0x112, 0xf, 0xf, false);
  v += __int_as_float(x);
  x = __builtin_amdgcn_update_dpp(0, __float_as_int(v), 0x114, 0xf, 0xf, false);
  v += __int_as_float(x);
  x = __builtin_amdgcn_update_dpp(0, __float_as_int(v), 0x118, 0xf, 0xf, false);
  v += __int_as_float(x);
  x = __builtin_amdgcn_update_dpp(0, __float_as_int(v), 0x142, 0xa, 0xf, false);
  v += __int_as_float(x);
  x = __builtin_amdgcn_update_dpp(0, __float_as_int(v), 0x143, 0xc, 0xf, false);
  v += __int_as_float(x);
  return __int_as_float(__builtin_amdgcn_readlane(__float_as_int(v), 63));
}

// bare v_exp_f32: D = 2^x  (softmax runs in log2 domain)
__device__ __forceinline__ float exp2_fast(float x) {
  float r;
  asm("v_exp_f32 %0, %1" : "=v"(r) : "v"(x));
  return r;
}

// Batched reduction of FOUR 64-lane vectors -> four wave-uniform sums.
// permlane32_swap folds pairs; one asm block of 10 v_add_f32_dpp with the two
// independent chains interleaved (covers DPP wait-states). Totals at lanes 31/63.
__device__ __forceinline__ void red4(float q0, float q1, float q2, float q3,
                                     float& p0, float& p1, float& p2, float& p3) {
  asm("s_nop 1\n\tv_permlane32_swap_b32 %0, %1" : "+v"(q0), "+v"(q1));
  float ra = q0 + q1;
  asm("s_nop 1\n\tv_permlane32_swap_b32 %0, %1" : "+v"(q2), "+v"(q3));
  float rb = q2 + q3;
  asm("s_nop 1\n\t"
      "v_add_f32_dpp %0, %0, %0 row_shr:1 row_mask:0xf bank_mask:0xf bound_ctrl:0\n\t"
      "v_add_f32_dpp %1, %1, %1 row_shr:1 row_mask:0xf bank_mask:0xf bound_ctrl:0\n\t"
      "v_add_f32_dpp %0, %0, %0 row_shr:2 row_mask:0xf bank_mask:0xf bound_ctrl:0\n\t"
      "v_add_f32_dpp %1, %1, %1 row_shr:2 row_mask:0xf bank_mask:0xf bound_ctrl:0\n\t"
      "v_add_f32_dpp %0, %0, %0 row_shr:4 row_mask:0xf bank_mask:0xf bound_ctrl:0\n\t"
      "v_add_f32_dpp %1, %1, %1 row_shr:4 row_mask:0xf bank_mask:0xf bound_ctrl:0\n\t"
      "v_add_f32_dpp %0, %0, %0 row_shr:8 row_mask:0xf bank_mask:0xf bound_ctrl:0\n\t"
      "v_add_f32_dpp %1, %1, %1 row_shr:8 row_mask:0xf bank_mask:0xf bound_ctrl:0\n\t"
      "v_add_f32_dpp %0, %0, %0 row_bcast:15 row_mask:0xa bank_mask:0xf bound_ctrl:0\n\t"
      "v_add_f32_dpp %1, %1, %1 row_bcast:15 row_mask:0xa bank_mask:0xf bound_ctrl:0\n\t"
      "s_nop 0"
      : "+v"(ra), "+v"(rb));
  p0 = __int_as_float(__builtin_amdgcn_readlane(__float_as_int(ra), 31));
  p1 = __int_as_float(__builtin_amdgcn_readlane(__float_as_int(ra), 63));
  p2 = __int_as_float(__builtin_amdgcn_readlane(__float_as_int(rb), 31));
  p3 = __int_as_float(__builtin_amdgcn_readlane(__float_as_int(rb), 63));
}

// P0 (blocks 0..15): Mt[c2*64+c1] = sum_k keyW[k,c1]*qryW[k,c2] (transposed).
// Block 16: aVec/bVec/c0/fk (fk pre-scaled by 0.25).
__global__ void prep_kernel(const float* __restrict__ keyW, const float* __restrict__ keyB,
                            const float* __restrict__ qryW, const float* __restrict__ qryB,
                            const float* __restrict__ fkb, const float* __restrict__ fkw,
                            float* __restrict__ Mt, float* __restrict__ aVec,
                            float* __restrict__ bVec, float* __restrict__ c0,
                            float* __restrict__ fk) {
  __shared__ float qw[KEYDD * CC];   // 32 KB
  __shared__ float kws[KEYDD * 4];   // 2 KB
  int t = threadIdx.x, b = blockIdx.x;
  if (b < 16) {
    for (int i = t; i < KEYDD * CC; i += 256) qw[i] = qryW[i];
    for (int i = t; i < KEYDD * 4; i += 256) {
      int k = i >> 2, c1l = i & 3;
      kws[i] = keyW[k * CC + b * 4 + c1l];
    }
    __syncthreads();
    int c1l = t >> 6, c2 = t & 63;
    float s = 0.f;
    #pragma unroll 8
    for (int k = 0; k < KEYDD; ++k)
      s = fmaf(kws[k * 4 + c1l], qw[k * CC + c2], s);
    Mt[c2 * CC + b * 4 + c1l] = s;
  } else {
    if (t < CC) {
      float sa = 0.f, sb = 0.f;
      for (int k = 0; k < KEYDD; ++k) {
        sa = fmaf(keyB[k], qryW[k * CC + t], sa);
        sb = fmaf(qryB[k], keyW[k * CC + t], sb);
      }
      aVec[t] = sa; bVec[t] = sb;
    }
    if (t == 0) {
      float s = 0.f;
      for (int k = 0; k < KEYDD; ++k) s = fmaf(keyB[k], qryB[k], s);
      c0[0] = s;
    }
    for (int idx = t; idx < OO * OO * CC; idx += 256) {
      int p = idx >> 8, rem = idx & 255;
      int o = rem >> 6, c = rem & 63;
      float s = 0.f;
      #pragma unroll
      for (int kd = 0; kd < KDD; ++kd)
        s = fmaf(fkb[(p * OO + o) * KDD + kd], fkw[c * KDD + kd], s);
      fk[idx] = 0.25f * s;  // fold the 1/O normalization here
    }
  }
}

// K2a: CSR degree counts
__global__ void count_kernel(const int* __restrict__ ei, int* __restrict__ counts) {
  int e = blockIdx.x * 256 + threadIdx.x;
  if (e < EE) atomicAdd(&counts[ei[EE + e]], 1);
}

// K2b: 3-dispatch parallel exclusive scan over counts[NN] -> offsets[NN+1]
__global__ void scan1_kernel(const int* __restrict__ counts, int* __restrict__ incl,
                             int* __restrict__ bsum, int n) {
  __shared__ int buf[256];
  int t = threadIdx.x;
  int i = blockIdx.x * 256 + t;
  int v = (i < n) ? counts[i] : 0;
  buf[t] = v;
  __syncthreads();
  for (int off = 1; off < 256; off <<= 1) {
    int a = buf[t];
    int b2 = (t >= off) ? buf[t - off] : 0;
    __syncthreads();
    buf[t] = a + b2;
    __syncthreads();
  }
  if (i < n) incl[i] = buf[t];
  if (t == 255) bsum[blockIdx.x] = buf[255];
}
__global__ void scan2_kernel(const int* __restrict__ bsum, int* __restrict__ bbase, int nb) {
  __shared__ int buf[256];
  int t = threadIdx.x;
  int v = (t < nb) ? bsum[t] : 0;
  buf[t] = v;
  __syncthreads();
  for (int off = 1; off < 256; off <<= 1) {
    int a = buf[t];
    int b2 = (t >= off) ? buf[t - off] : 0;
    __syncthreads();
    buf[t] = a + b2;
    __syncthreads();
  }
  if (t < nb) bbase[t] = buf[t] - v;  // exclusive
}
__global__ void scan3_kernel(const int* __restrict__ counts, const int* __restrict__ incl,
                             const int* __restrict__ bbase, int* __restrict__ offsets, int n) {
  int i = blockIdx.x * 256 + threadIdx.x;
  if (i < n) {
    int oi = bbase[blockIdx.x] + incl[i];
    offsets[i] = oi - counts[i];
    if (i == n - 1) offsets[n] = oi;
  }
}

// K2c: fill CSR as SPLIT arrays (edge id + src) so mega's index prefetch is a
// plain global_load_dword per array (full manual vmcnt-queue control).
__global__ void fill_kernel(const int* __restrict__ ei, const int* __restrict__ offsets,
                            int* __restrict__ counts, int* __restrict__ edge_list,
                            int* __restrict__ esrc) {
  int e = blockIdx.x * 256 + threadIdx.x;
  if (e < EE) {
    int d = ei[EE + e];
    int r = atomicSub(&counts[d], 1) - 1;
    int pos = offsets[d] + r;
    edge_list[pos] = e;
    esrc[pos] = ei[e];
  }
}

// kv = dot16(kb[ej, o, :], kW[c, :]) via PACKED f32 math: 8 v_pk_fma_f32
// + 1 pk_add + 1 add. ej is an SGPR -> loads go down the s_load (lgkmcnt)
// path, which does NOT interact with the manual vmcnt pipeline.
__device__ __forceinline__ float kv_dot(const float* __restrict__ kb, int ej, int obase,
                                        float4 kw0, float4 kw1, float4 kw2, float4 kw3) {
  const float4* bp = reinterpret_cast<const float4*>(kb + ej * (OO * KDD) + obase);
  float4 b0 = bp[0], b1 = bp[1], b2 = bp[2], b3 = bp[3];
  v2f a0 = {0.f, 0.f}, a1 = {0.f, 0.f};
  #define P2(f4, i) (reinterpret_cast<const v2f*>(&(f4))[i])
  a0 = __builtin_elementwise_fma(P2(b0, 0), P2(kw0, 0), a0);
  a1 = __builtin_elementwise_fma(P2(b0, 1), P2(kw0, 1), a1);
  a0 = __builtin_elementwise_fma(P2(b1, 0), P2(kw1, 0), a0);
  a1 = __builtin_elementwise_fma(P2(b1, 1), P2(kw1, 1), a1);
  a0 = __builtin_elementwise_fma(P2(b2, 0), P2(kw2, 0), a0);
  a1 = __builtin_elementwise_fma(P2(b2, 1), P2(kw2, 1), a1);
  a0 = __builtin_elementwise_fma(P2(b3, 0), P2(kw3, 0), a0);
  a1 = __builtin_elementwise_fma(P2(b3, 1), P2(kw3, 1), a1);
  #undef P2
  v2f s = a0 + a1;
  return s.x + s.y;
}

// K3: MEGA — CROSS-CHUNK SOFTWARE PIPELINE on the proven asm frame.
// R11/R13/R14 showed wall time pinned at ~370us while VALU work shrank:
// the binding stall is the per-chunk vmcnt(0) drain exposing gather latency.
// Now EVERY VMEM op in the loop is volatile asm (gathers AND index loads):
// per iteration, issue next chunk's 16 gathers + next-next chunk's idx loads,
// then compute the current chunk from registers. The single vmcnt(0) at the
// iteration top has the whole previous compute phase (~640cy) behind it.
// Hazards: edge ids are extracted to SGPRs (constant-lane readlanes) BEFORE
// their VGPR is re-targeted by the next-next idx load; xvA/xvB ping-pong with
// static names; sched_barrier(0) fences after each waitcnt (rule #18).
// R9's version of this idea failed because the COMPILER managed the loads
// (queue entanglement + regalloc collapse); the asm frame pins both.
__global__ __launch_bounds__(256, 4) void mega_kernel(
    const float* __restrict__ x, const float* __restrict__ Mt,
    const float* __restrict__ aVec, const float* __restrict__ bVec,
    const float* __restrict__ c0p, const float* __restrict__ kb,
    const float* __restrict__ kW, const int* __restrict__ offsets,
    const int* __restrict__ edge_list, const int* __restrict__ esrc,
    const float* __restrict__ fkg, const float* __restrict__ bias,
    float* __restrict__ out) {
  __shared__ float x1[OO * CC];
  int n = blockIdx.x;
  int t = threadIdx.x;
  int o = __builtin_amdgcn_readfirstlane(t >> 6);
  int c = t & 63;
  const float scale2 = 0.12751541050862828f;  // (1/sqrt(128)) * log2(e)
  int js = offsets[n], je = offsets[n + 1];
  int deg = je - js;
  int lane16 = c & 15;

  // idx(chunk 0): issue FIRST so the long ub compute hides it
  int eA = 0, sA = 0, eB = 0, sB = 0;
  if (deg > 0) {
    int q0 = (js + min(lane16, deg - 1)) << 2;
    asm volatile("global_load_dword %0, %1, %2" : "=v"(eA) : "v"(q0), "s"(edge_list));
    asm volatile("global_load_dword %0, %1, %2" : "=v"(sA) : "v"(q0), "s"(esrc));
  }

  // ub = (Mt^T xrow + bVec) * scale2 — scalar-pipe xrow, 4 split chains (R14)
  int rowoff = __builtin_amdgcn_readfirstlane((n * OO + o) * CC);
  const float* xrow = x + rowoff;
  float ub0 = 0.f, ub1 = 0.f, ub2 = 0.f, ub3 = 0.f;
  #pragma unroll
  for (int q = 0; q < 16; ++q) {
    ub0 = fmaf(Mt[(4 * q + 0) * CC + c], xrow[4 * q + 0], ub0);
    ub1 = fmaf(Mt[(4 * q + 1) * CC + c], xrow[4 * q + 1], ub1);
    ub2 = fmaf(Mt[(4 * q + 2) * CC + c], xrow[4 * q + 2], ub2);
    ub3 = fmaf(Mt[(4 * q + 3) * CC + c], xrow[4 * q + 3], ub3);
  }
  float ubr = (((ub0 + ub1) + (ub2 + ub3)) + bVec[c]) * scale2;
  float xown = xrow[c];
  float base2 = (wave_red_sum(aVec[c] * xown) + c0p[0]) * scale2;

  const float4* kwp = reinterpret_cast<const float4*>(kW + c * KDD);
  float4 kw0 = kwp[0], kw1 = kwp[1], kw2 = kwp[2], kw3 = kwp[3];
  int obase = o * KDD;
  int voff = c << 2;

  float S = 0.f, acc = 0.f;
  float xvA[CH], xvB[CH];

  #define GATHER(XV, SV)                                                       \
  {                                                                            \
    _Pragma("unroll")                                                          \
    for (int j = 0; j < CH; ++j) {                                             \
      int sj = __builtin_amdgcn_readlane(SV, j);                               \
      const float* pj = x + (size_t)(sj * OO + o) * CC;                        \
      asm volatile("global_load_dword %0, %1, %2"                              \
                   : "=v"(XV[j]) : "v"(voff), "s"(pj));                        \
    }                                                                          \
  }
  #define SUB4(XV, ES, J0, CL)                                                 \
  {                                                                            \
    float kv0 = kv_dot(kb, ES[(J0) + 0], obase, kw0, kw1, kw2, kw3);           \
    float kv1 = kv_dot(kb, ES[(J0) + 1], obase, kw0, kw1, kw2, kw3);           \
    float kv2 = kv_dot(kb, ES[(J0) + 2], obase, kw0, kw1, kw2, kw3);           \
    float kv3 = kv_dot(kb, ES[(J0) + 3], obase, kw0, kw1, kw2, kw3);           \
    float p0, p1, p2, p3;                                                      \
    red4(XV[(J0) + 0] * ubr, XV[(J0) + 1] * ubr,                               \
         XV[(J0) + 2] * ubr, XV[(J0) + 3] * ubr, p0, p1, p2, p3);              \
    float ev0 = ((J0) + 0 < (CL)) ? exp2_fast(p0) : 0.f;                       \
    float ev1 = ((J0) + 1 < (CL)) ? exp2_fast(p1) : 0.f;                       \
    float ev2 = ((J0) + 2 < (CL)) ? exp2_fast(p2) : 0.f;                       \
    float ev3 = ((J0) + 3 < (CL)) ? exp2_fast(p3) : 0.f;                       \
    S += (ev0 + ev1) + (ev2 + ev3);                                            \
    acc = fmaf(ev0 * kv0, XV[(J0) + 0], acc);                                  \
    acc = fmaf(ev1 * kv1, XV[(J0) + 1], acc);                                  \
    acc = fmaf(ev2 * kv2, XV[(J0) + 2], acc);                                  \
    acc = fmaf(ev3 * kv3, XV[(J0) + 3], acc);                                  \
  }
  #define COMPUTE(XV, ES, CL)                                                  \
    SUB4(XV, ES, 0, CL)                                                        \
    if ((CL) > 4)  SUB4(XV, ES, 4, CL)                                         \
    if ((CL) > 8)  SUB4(XV, ES, 8, CL)                                         \
    if ((CL) > 12) SUB4(XV, ES, 12, CL)

  if (deg > 0) {
    asm volatile("s_waitcnt vmcnt(0)" ::: "memory");  // idx(0) done
    __builtin_amdgcn_sched_barrier(0);
    GATHER(xvA, sA)                                   // gathers(0) in flight
    if (CH < deg) {                                   // idx(1) in flight
      int rem = deg - CH;
      int q1 = (js + CH + min(lane16, rem - 1)) << 2;
      asm volatile("global_load_dword %0, %1, %2" : "=v"(eB) : "v"(q1), "s"(edge_list));
      asm volatile("global_load_dword %0, %1, %2" : "=v"(sB) : "v"(q1), "s"(esrc));
    }
    int cs = 0;
    while (true) {
      // ---- chunk cs: data xvA, ids eA ----
      asm volatile("s_waitcnt vmcnt(0)" ::: "memory");  // xvA + idx(next) ready
      __builtin_amdgcn_sched_barrier(0);
      int cl = deg - cs; if (cl > CH) cl = CH;
      int esA[CH];
      #pragma unroll
      for (int j = 0; j < CH; ++j) esA[j] = __builtin_amdgcn_readlane(eA, j);
      bool hasNext = (cs + CH) < deg;
      if (hasNext) {
        GATHER(xvB, sB)                               // gathers(cs+CH)
        int ns2 = cs + 2 * CH;
        if (ns2 < deg) {                              // idx(cs+2CH) -> A slot
          int rem2 = deg - ns2;
          int q2 = (js + ns2 + min(lane16, rem2 - 1)) << 2;
          asm volatile("global_load_dword %0, %1, %2" : "=v"(eA) : "v"(q2), "s"(edge_list));
          asm volatile("global_load_dword %0, %1, %2" : "=v"(sA) : "v"(q2), "s"(esrc));
        }
      }
      __builtin_amdgcn_sched_barrier(0);
      COMPUTE(xvA, esA, cl)
      if (!hasNext) break;
      cs += CH;
      // ---- chunk cs: data xvB, ids eB ----
      asm volatile("s_waitcnt vmcnt(0)" ::: "memory");
      __builtin_amdgcn_sched_barrier(0);
      cl = deg - cs; if (cl > CH) cl = CH;
      int esB[CH];
      #pragma unroll
      for (int j = 0; j < CH; ++j) esB[j] = __builtin_amdgcn_readlane(eB, j);
      hasNext = (cs + CH) < deg;
      if (hasNext) {
        GATHER(xvA, sA)                               // gathers(cs+CH)
        int ns2 = cs + 2 * CH;
        if (ns2 < deg) {                              // idx(cs+2CH) -> B slot
          int rem2 = deg - ns2;
          int q2 = (js + ns2 + min(lane16, rem2 - 1)) << 2;
          asm volatile("global_load_dword %0, %1, %2" : "=v"(eB) : "v"(q2), "s"(edge_list));
          asm volatile("global_load_dword %0, %1, %2" : "=v"(sB) : "v"(q2), "s"(esrc));
        }
      }
      __builtin_amdgcn_sched_barrier(0);
      COMPUTE(xvB, esB, cl)
      if (!hasNext) break;
      cs += CH;
    }
  }
  #undef COMPUTE
  #undef SUB4
  #undef GATHER

  // epsilon restored in the unshifted-logit domain: denom = S + 1e-6*2^(-base2)
  float invd = 1.0f / (S + 1e-6f * exp2_fast(-base2));
  x1[t] = acc * invd;
  __syncthreads();
  // fiber mix: out[n,p=o,c] = sum_oo x1[oo,c]*fk[o,oo,c] + bias[c]  (0.25 in fk)
  float s2s = 0.f;
  #pragma unroll
  for (int oo = 0; oo < OO; ++oo)
    s2s = fmaf(x1[oo * CC + c], fkg[o * (OO * CC) + oo * CC + c], s2s);
  out[(size_t)n * (OO * CC) + t] = s2s + bias[c];
}

extern "C" void kernel_launch(void* const* d_in, const int* in_sizes, int n_in,
                              void* d_out, int out_size, void* d_ws, size_t ws_size,
                              hipStream_t stream) {
  const float* x    = (const float*)d_in[0];
  const float* kb   = (const float*)d_in[1];
  const float* fkb  = (const float*)d_in[2];
  const int*   ei   = (const int*)d_in[3];
  const float* kW   = (const float*)d_in[4];
  const float* fkW  = (const float*)d_in[5];
  const float* keyW = (const float*)d_in[6];
  const float* keyB = (const float*)d_in[7];
  const float* qryW = (const float*)d_in[8];
  const float* qryB = (const float*)d_in[9];
  const float* bias = (const float*)d_in[10];
  float* out = (float*)d_out;

  const int NB = (NN + 255) / 256;  // 196 scan blocks

  float* wsf  = (float*)d_ws;
  float* Mt   = wsf;                          // 4096
  float* aVec = Mt + 4096;                    // 64
  float* bVec = aVec + 64;                    // 64
  float* c0   = bVec + 64;                    // 1 (+63 pad)
  float* fk   = c0 + 64;                      // 1024
  int* edge_list = (int*)(fk + 1024);         // EE
  int* esrc      = edge_list + EE;            // EE
  int* counts    = esrc + EE;                 // 50000
  int* offsets   = counts + NN;               // 50001
  int* incl      = offsets + NN + 1;          // 50000
  int* bsum      = incl + NN;                 // NB
  int* bbase     = bsum + 256;                // NB

  hipMemsetAsync(counts, 0, (size_t)NN * sizeof(int), stream);

  prep_kernel<<<17, 256, 0, stream>>>(keyW, keyB, qryW, qryB, fkb, fkW, Mt, aVec, bVec, c0, fk);
  count_kernel<<<(EE + 255) / 256, 256, 0, stream>>>(ei, counts);
  scan1_kernel<<<NB, 256, 0, stream>>>(counts, incl, bsum, NN);
  scan2_kernel<<<1, 256, 0, stream>>>(bsum, bbase, NB);
  scan3_kernel<<<NB, 256, 0, stream>>>(counts, incl, bbase, offsets, NN);
  fill_kernel<<<(EE + 255) / 256, 256, 0, stream>>>(ei, offsets, counts, edge_list, esrc);
  mega_kernel<<<NN, 256, 0, stream>>>(x, Mt, aVec, bVec, c0, kb, kW, offsets,
                                      edge_list, esrc, fk, bias, out);
}

// Round 16
// 436.385 us; speedup vs baseline: 3.6225x; 3.6225x over previous
//
#include <hip/hip_runtime.h>
#include <math.h>

#define NN 50000
#define EE 800000
#define OO 4
#define CC 64
#define KDD 16
#define KEYDD 128
#define CH 16  // edges per chunk

typedef float v2f __attribute__((ext_vector_type(2)));

// Full-wave (64-lane) sum via DPP builtins (prologue only)
__device__ __forceinline__ float wave_red_sum(float v) {
  int x;
  x = __builtin_amdgcn_update_dpp(0, __float_as_int(v), 0x111, 0xf, 0xf, false);
  v += __int_as_float(x);
  x = __builtin_amdgcn_update_dpp(0, __float_as_int(v), 0x112, 0xf, 0xf, false);
  v += __int_as_float(x);
  x = __builtin_amdgcn_update_dpp(0, __float_as_int(v), 0x114, 0xf, 0xf, false);
  v += __int_as_float(x);
  x = __builtin_amdgcn_update_dpp(0, __float_as_int(v), 0x118, 0xf, 0xf, false);
  v += __int_as_float(x);
  x = __builtin_amdgcn_update_dpp(0, __float_as_int(v), 0x142, 0xa, 0xf, false);
  v += __int_as_float(x);
  x = __builtin_amdgcn_update_dpp(0, __float_as_int(v), 0x143, 0xc, 0xf, false);
  v += __int_as_float(x);
  return __int_as_float(__builtin_amdgcn_readlane(__float_as_int(v), 63));
}

// bare v_exp_f32: D = 2^x  (softmax runs in log2 domain)
__device__ __forceinline__ float exp2_fast(float x) {
  float r;
  asm("v_exp_f32 %0, %1" : "=v"(r) : "v"(x));
  return r;
}

// Batched reduction of FOUR 64-lane vectors -> four wave-uniform sums.
__device__ __forceinline__ void red4(float q0, float q1, float q2, float q3,
                                     float& p0, float& p1, float& p2, float& p3) {
  asm("s_nop 1\n\tv_permlane32_swap_b32 %0, %1" : "+v"(q0), "+v"(q1));
  float ra = q0 + q1;
  asm("s_nop 1\n\tv_permlane32_swap_b32 %0, %1" : "+v"(q2), "+v"(q3));
  float rb = q2 + q3;
  asm("s_nop 1\n\t"
      "v_add_f32_dpp %0, %0, %0 row_shr:1 row_mask:0xf bank_mask:0xf bound_ctrl:0\n\t"
      "v_add_f32_dpp %1, %1, %1 row_shr:1 row_mask:0xf bank_mask:0xf bound_ctrl:0\n\t"
      "v_add_f32_dpp %0, %0, %0 row_shr:2 row_mask:0xf bank_mask:0xf bound_ctrl:0\n\t"
      "v_add_f32_dpp %1, %1, %1 row_shr:2 row_mask:0xf bank_mask:0xf bound_ctrl:0\n\t"
      "v_add_f32_dpp %0, %0, %0 row_shr:4 row_mask:0xf bank_mask:0xf bound_ctrl:0\n\t"
      "v_add_f32_dpp %1, %1, %1 row_shr:4 row_mask:0xf bank_mask:0xf bound_ctrl:0\n\t"
      "v_add_f32_dpp %0, %0, %0 row_shr:8 row_mask:0xf bank_mask:0xf bound_ctrl:0\n\t"
      "v_add_f32_dpp %1, %1, %1 row_shr:8 row_mask:0xf bank_mask:0xf bound_ctrl:0\n\t"
      "v_add_f32_dpp %0, %0, %0 row_bcast:15 row_mask:0xa bank_mask:0xf bound_ctrl:0\n\t"
      "v_add_f32_dpp %1, %1, %1 row_bcast:15 row_mask:0xa bank_mask:0xf bound_ctrl:0\n\t"
      "s_nop 0"
      : "+v"(ra), "+v"(rb));
  p0 = __int_as_float(__builtin_amdgcn_readlane(__float_as_int(ra), 31));
  p1 = __int_as_float(__builtin_amdgcn_readlane(__float_as_int(ra), 63));
  p2 = __int_as_float(__builtin_amdgcn_readlane(__float_as_int(rb), 31));
  p3 = __int_as_float(__builtin_amdgcn_readlane(__float_as_int(rb), 63));
}

// async 16B global -> LDS copy (vmcnt-tracked; LDS dest = base + lane*16)
__device__ __forceinline__ void async_cp16(const float* gsrc, float* ldst) {
  __builtin_amdgcn_global_load_lds(
      (const __attribute__((address_space(1))) unsigned int*)gsrc,
      (__attribute__((address_space(3))) unsigned int*)ldst, 16, 0, 0);
}

// P0 (blocks 0..15): Mt[c2*64+c1] (transposed). Block 16: aVec/bVec/c0/fk (0.25-folded).
__global__ void prep_kernel(const float* __restrict__ keyW, const float* __restrict__ keyB,
                            const float* __restrict__ qryW, const float* __restrict__ qryB,
                            const float* __restrict__ fkb, const float* __restrict__ fkw,
                            float* __restrict__ Mt, float* __restrict__ aVec,
                            float* __restrict__ bVec, float* __restrict__ c0,
                            float* __restrict__ fk) {
  __shared__ float qw[KEYDD * CC];   // 32 KB
  __shared__ float kws[KEYDD * 4];   // 2 KB
  int t = threadIdx.x, b = blockIdx.x;
  if (b < 16) {
    for (int i = t; i < KEYDD * CC; i += 256) qw[i] = qryW[i];
    for (int i = t; i < KEYDD * 4; i += 256) {
      int k = i >> 2, c1l = i & 3;
      kws[i] = keyW[k * CC + b * 4 + c1l];
    }
    __syncthreads();
    int c1l = t >> 6, c2 = t & 63;
    float s = 0.f;
    #pragma unroll 8
    for (int k = 0; k < KEYDD; ++k)
      s = fmaf(kws[k * 4 + c1l], qw[k * CC + c2], s);
    Mt[c2 * CC + b * 4 + c1l] = s;
  } else {
    if (t < CC) {
      float sa = 0.f, sb = 0.f;
      for (int k = 0; k < KEYDD; ++k) {
        sa = fmaf(keyB[k], qryW[k * CC + t], sa);
        sb = fmaf(qryB[k], keyW[k * CC + t], sb);
      }
      aVec[t] = sa; bVec[t] = sb;
    }
    if (t == 0) {
      float s = 0.f;
      for (int k = 0; k < KEYDD; ++k) s = fmaf(keyB[k], qryB[k], s);
      c0[0] = s;
    }
    for (int idx = t; idx < OO * OO * CC; idx += 256) {
      int p = idx >> 8, rem = idx & 255;
      int o = rem >> 6, c = rem & 63;
      float s = 0.f;
      #pragma unroll
      for (int kd = 0; kd < KDD; ++kd)
        s = fmaf(fkb[(p * OO + o) * KDD + kd], fkw[c * KDD + kd], s);
      fk[idx] = 0.25f * s;
    }
  }
}

// K2a: CSR degree counts
__global__ void count_kernel(const int* __restrict__ ei, int* __restrict__ counts) {
  int e = blockIdx.x * 256 + threadIdx.x;
  if (e < EE) atomicAdd(&counts[ei[EE + e]], 1);
}

// K2b: 3-dispatch parallel exclusive scan
__global__ void scan1_kernel(const int* __restrict__ counts, int* __restrict__ incl,
                             int* __restrict__ bsum, int n) {
  __shared__ int buf[256];
  int t = threadIdx.x;
  int i = blockIdx.x * 256 + t;
  int v = (i < n) ? counts[i] : 0;
  buf[t] = v;
  __syncthreads();
  for (int off = 1; off < 256; off <<= 1) {
    int a = buf[t];
    int b2 = (t >= off) ? buf[t - off] : 0;
    __syncthreads();
    buf[t] = a + b2;
    __syncthreads();
  }
  if (i < n) incl[i] = buf[t];
  if (t == 255) bsum[blockIdx.x] = buf[255];
}
__global__ void scan2_kernel(const int* __restrict__ bsum, int* __restrict__ bbase, int nb) {
  __shared__ int buf[256];
  int t = threadIdx.x;
  int v = (t < nb) ? bsum[t] : 0;
  buf[t] = v;
  __syncthreads();
  for (int off = 1; off < 256; off <<= 1) {
    int a = buf[t];
    int b2 = (t >= off) ? buf[t - off] : 0;
    __syncthreads();
    buf[t] = a + b2;
    __syncthreads();
  }
  if (t < nb) bbase[t] = buf[t] - v;
}
__global__ void scan3_kernel(const int* __restrict__ counts, const int* __restrict__ incl,
                             const int* __restrict__ bbase, int* __restrict__ offsets, int n) {
  int i = blockIdx.x * 256 + threadIdx.x;
  if (i < n) {
    int oi = bbase[blockIdx.x] + incl[i];
    offsets[i] = oi - counts[i];
    if (i == n - 1) offsets[n] = oi;
  }
}

// K2c: fill CSR as packed (src<<32 | eid) pairs; reuses counts as cursor.
__global__ void fill_kernel(const int* __restrict__ ei, const int* __restrict__ offsets,
                            int* __restrict__ counts, long long* __restrict__ pairs) {
  int e = blockIdx.x * 256 + threadIdx.x;
  if (e < EE) {
    int d = ei[EE + e];
    int r = atomicSub(&counts[d], 1) - 1;
    int pos = offsets[d] + r;
    pairs[pos] = ((long long)ei[e] << 32) | (unsigned)e;
  }
}

// kv = dot16 from an LDS row (wave-uniform address -> broadcast ds_read_b128 x4).
__device__ __forceinline__ float kv_dot_lds(const float* row,
                                            float4 kw0, float4 kw1, float4 kw2, float4 kw3) {
  const float4* bp = reinterpret_cast<const float4*>(row);
  float4 b0 = bp[0], b1 = bp[1], b2 = bp[2], b3 = bp[3];
  v2f a0 = {0.f, 0.f}, a1 = {0.f, 0.f};
  #define P2(f4, i) (reinterpret_cast<const v2f*>(&(f4))[i])
  a0 = __builtin_elementwise_fma(P2(b0, 0), P2(kw0, 0), a0);
  a1 = __builtin_elementwise_fma(P2(b0, 1), P2(kw0, 1), a1);
  a0 = __builtin_elementwise_fma(P2(b1, 0), P2(kw1, 0), a0);
  a1 = __builtin_elementwise_fma(P2(b1, 1), P2(kw1, 1), a1);
  a0 = __builtin_elementwise_fma(P2(b2, 0), P2(kw2, 0), a0);
  a1 = __builtin_elementwise_fma(P2(b2, 1), P2(kw2, 1), a1);
  a0 = __builtin_elementwise_fma(P2(b3, 0), P2(kw3, 0), a0);
  a1 = __builtin_elementwise_fma(P2(b3, 1), P2(kw3, 1), a1);
  #undef P2
  v2f s = a0 + a1;
  return s.x + s.y;
}

// K3: MEGA — R14 frame (best: 368us) + kb staged through LDS one chunk ahead.
// THEORY: R13 proved xv-gather batching is latency-hidden by TLP; the residual
// 46% stall is kv_dot's s_load_dwordx4 chains (random 256B kb slices through
// the tiny scalar cache, ~300-500cy each, inside the compute phase).
// FIX: per chunk each wave issues ONE async global_load_lds (16B/lane; 4 edge
// rows of 256B per wave, linear lane->dest mapping) staging the NEXT chunk's
// kb into kbL[buf^1]. The existing per-chunk vmcnt(0)+barrier drains it; the
// compute phase then reads kv via broadcast ds_read_b128 (local, pipelined).
// Buffer lifetime: write buf^1 happens after the barrier that ends all reads
// of buf^1 from the previous chunk -> double buffer + 1 barrier/chunk is safe.
// R15 lesson: NO xv ping-pong (spilled, 2.2GB scratch); xv stays single-batch.
__global__ __launch_bounds__(256, 4) void mega_kernel(
    const float* __restrict__ x, const float* __restrict__ Mt,
    const float* __restrict__ aVec, const float* __restrict__ bVec,
    const float* __restrict__ c0p, const float* __restrict__ kb,
    const float* __restrict__ kW, const int* __restrict__ offsets,
    const long long* __restrict__ pairs, const float* __restrict__ fkg,
    const float* __restrict__ bias, float* __restrict__ out) {
  __shared__ float kbL[2][CH * 64];  // 8 KB: staged kb rows, [buf][j*64 + d]
  __shared__ float x1[OO * CC];
  int n = blockIdx.x;
  int t = threadIdx.x;
  int o = __builtin_amdgcn_readfirstlane(t >> 6);
  int c = t & 63;
  const float scale2 = 0.12751541050862828f;  // (1/sqrt(128)) * log2(e)
  int js = offsets[n], je = offsets[n + 1];
  int deg = je - js;
  int lane16 = c & 15;

  long long prA = 0;
  if (deg > 0) prA = pairs[js + min(lane16, deg - 1)];  // chunk-0, in flight early

  // ub = (Mt^T xrow + bVec) * scale2 — scalar-pipe xrow, 4 split chains (R14)
  int rowoff = __builtin_amdgcn_readfirstlane((n * OO + o) * CC);
  const float* xrow = x + rowoff;
  float ub0 = 0.f, ub1 = 0.f, ub2 = 0.f, ub3 = 0.f;
  #pragma unroll
  for (int q = 0; q < 16; ++q) {
    ub0 = fmaf(Mt[(4 * q + 0) * CC + c], xrow[4 * q + 0], ub0);
    ub1 = fmaf(Mt[(4 * q + 1) * CC + c], xrow[4 * q + 1], ub1);
    ub2 = fmaf(Mt[(4 * q + 2) * CC + c], xrow[4 * q + 2], ub2);
    ub3 = fmaf(Mt[(4 * q + 3) * CC + c], xrow[4 * q + 3], ub3);
  }
  float ubr = (((ub0 + ub1) + (ub2 + ub3)) + bVec[c]) * scale2;
  float xown = xrow[c];
  float base2 = (wave_red_sum(aVec[c] * xown) + c0p[0]) * scale2;

  const float4* kwp = reinterpret_cast<const float4*>(kW + c * KDD);
  float4 kw0 = kwp[0], kw1 = kwp[1], kw2 = kwp[2], kw3 = kwp[3];
  int obase = o * KDD;
  int voff = c << 2;
  int w4 = o * 4;          // this wave stages edges w4..w4+3
  int ksel = c >> 4;       // 0..3: which of the 4 edges this lane serves

  // per-wave stage of one chunk's kb rows into kbL[buf] (1 async op per lane)
  #define STAGE(BUF, EV)                                                       \
  {                                                                            \
    int e0 = __builtin_amdgcn_readlane(EV, w4 + 0);                            \
    int e1 = __builtin_amdgcn_readlane(EV, w4 + 1);                            \
    int e2 = __builtin_amdgcn_readlane(EV, w4 + 2);                            \
    int e3 = __builtin_amdgcn_readlane(EV, w4 + 3);                            \
    int elo = (ksel & 1) ? e1 : e0;                                            \
    int ehi = (ksel & 1) ? e3 : e2;                                            \
    int es = (ksel & 2) ? ehi : elo;                                           \
    async_cp16(kb + (size_t)es * 64 + (c & 15) * 4, &kbL[BUF][w4 * 64]);       \
  }

  float S = 0.f, acc = 0.f;

  if (deg > 0) {
    int eA0 = (int)((unsigned long long)prA & 0xffffffffu);
    STAGE(0, eA0)  // chunk 0's kb, async
  }
  long long prB = 0;
  if (CH < deg) prB = pairs[js + CH + min(lane16, deg - CH - 1)];

  for (int cs = 0; cs < deg; cs += CH) {
    int cl = deg - cs; if (cl > CH) cl = CH;  // wave-uniform
    int buf = (cs >> 4) & 1;
    int s_v = (int)(prA >> 32);
    float xv[CH];
    // 1) forced 16-wide x gather batch (R13 frame)
    #pragma unroll
    for (int j = 0; j < CH; ++j) {
      int sj = __builtin_amdgcn_readlane(s_v, j);
      const float* pj = x + (size_t)(sj * OO + o) * CC;
      asm volatile("global_load_dword %0, %1, %2"
                   : "=v"(xv[j]) : "v"(voff), "s"(pj));
    }
    asm volatile("s_waitcnt vmcnt(0)" ::: "memory");  // xv + this-chunk kb DMA done
    __builtin_amdgcn_sched_barrier(0);
    __syncthreads();  // kbL[buf] visible from all waves' DMAs
    // 2) stage NEXT chunk's kb + rotate pair prefetch
    bool hasNext = (cs + CH) < deg;
    if (hasNext) {
      int eN = (int)((unsigned long long)prB & 0xffffffffu);
      STAGE(buf ^ 1, eN)
    }
    prA = prB;
    int ns2 = cs + 2 * CH;
    if (ns2 < deg) prB = pairs[js + ns2 + min(lane16, deg - ns2 - 1)];
    __builtin_amdgcn_sched_barrier(0);
    // 3) compute: kv from LDS broadcasts, no-max softmax (R14)
    #define SUB4(J0)                                                           \
    {                                                                          \
      float kv0 = kv_dot_lds(&kbL[buf][((J0) + 0) * 64 + obase], kw0, kw1, kw2, kw3); \
      float kv1 = kv_dot_lds(&kbL[buf][((J0) + 1) * 64 + obase], kw0, kw1, kw2, kw3); \
      float kv2 = kv_dot_lds(&kbL[buf][((J0) + 2) * 64 + obase], kw0, kw1, kw2, kw3); \
      float kv3 = kv_dot_lds(&kbL[buf][((J0) + 3) * 64 + obase], kw0, kw1, kw2, kw3); \
      float p0, p1, p2, p3;                                                    \
      red4(xv[(J0) + 0] * ubr, xv[(J0) + 1] * ubr,                             \
           xv[(J0) + 2] * ubr, xv[(J0) + 3] * ubr, p0, p1, p2, p3);            \
      float ev0 = ((J0) + 0 < cl) ? exp2_fast(p0) : 0.f;                       \
      float ev1 = ((J0) + 1 < cl) ? exp2_fast(p1) : 0.f;                       \
      float ev2 = ((J0) + 2 < cl) ? exp2_fast(p2) : 0.f;                       \
      float ev3 = ((J0) + 3 < cl) ? exp2_fast(p3) : 0.f;                       \
      S += (ev0 + ev1) + (ev2 + ev3);                                          \
      acc = fmaf(ev0 * kv0, xv[(J0) + 0], acc);                                \
      acc = fmaf(ev1 * kv1, xv[(J0) + 1], acc);                                \
      acc = fmaf(ev2 * kv2, xv[(J0) + 2], acc);                                \
      acc = fmaf(ev3 * kv3, xv[(J0) + 3], acc);                                \
    }
    SUB4(0)
    if (cl > 4)  SUB4(4)
    if (cl > 8)  SUB4(8)
    if (cl > 12) SUB4(12)
    #undef SUB4
  }
  #undef STAGE

  // epsilon restored in the unshifted-logit domain
  float invd = 1.0f / (S + 1e-6f * exp2_fast(-base2));
  x1[t] = acc * invd;
  __syncthreads();
  float s2s = 0.f;
  #pragma unroll
  for (int oo = 0; oo < OO; ++oo)
    s2s = fmaf(x1[oo * CC + c], fkg[o * (OO * CC) + oo * CC + c], s2s);
  out[(size_t)n * (OO * CC) + t] = s2s + bias[c];
}

extern "C" void kernel_launch(void* const* d_in, const int* in_sizes, int n_in,
                              void* d_out, int out_size, void* d_ws, size_t ws_size,
                              hipStream_t stream) {
  const float* x    = (const float*)d_in[0];
  const float* kb   = (const float*)d_in[1];
  const float* fkb  = (const float*)d_in[2];
  const int*   ei   = (const int*)d_in[3];
  const float* kW   = (const float*)d_in[4];
  const float* fkW  = (const float*)d_in[5];
  const float* keyW = (const float*)d_in[6];
  const float* keyB = (const float*)d_in[7];
  const float* qryW = (const float*)d_in[8];
  const float* qryB = (const float*)d_in[9];
  const float* bias = (const float*)d_in[10];
  float* out = (float*)d_out;

  const int NB = (NN + 255) / 256;

  float* wsf  = (float*)d_ws;
  float* Mt   = wsf;                          // 4096
  float* aVec = Mt + 4096;                    // 64
  float* bVec = aVec + 64;                    // 64
  float* c0   = bVec + 64;                    // 1 (+63 pad)
  float* fk   = c0 + 64;                      // 1024
  long long* pairs = (long long*)(fk + 1024); // EE * 8B
  int* counts    = (int*)(pairs + EE);        // 50000
  int* offsets   = counts + NN;               // 50001
  int* incl      = offsets + NN + 1;          // 50000
  int* bsum      = incl + NN;                 // NB
  int* bbase     = bsum + 256;                // NB

  hipMemsetAsync(counts, 0, (size_t)NN * sizeof(int), stream);

  prep_kernel<<<17, 256, 0, stream>>>(keyW, keyB, qryW, qryB, fkb, fkW, Mt, aVec, bVec, c0, fk);
  count_kernel<<<(EE + 255) / 256, 256, 0, stream>>>(ei, counts);
  scan1_kernel<<<NB, 256, 0, stream>>>(counts, incl, bsum, NN);
  scan2_kernel<<<1, 256, 0, stream>>>(bsum, bbase, NB);
  scan3_kernel<<<NB, 256, 0, stream>>>(counts, incl, bbase, offsets, NN);
  fill_kernel<<<(EE + 255) / 256, 256, 0, stream>>>(ei, offsets, counts, pairs);
  mega_kernel<<<NN, 256, 0, stream>>>(x, Mt, aVec, bVec, c0, kb, kW, offsets, pairs,
                                      fk, bias, out);
}